// Round 18
// baseline (260.354 us; speedup 1.0000x reference)
//
#include <hip/hip_runtime.h>

#define LOG2E 1.44269504088896340736f

typedef _Float16 half8 __attribute__((ext_vector_type(8)));
typedef _Float16 half4v __attribute__((ext_vector_type(4)));
typedef float f32x16 __attribute__((ext_vector_type(16)));
typedef unsigned int uv4 __attribute__((ext_vector_type(4)));

__device__ __forceinline__ unsigned pk16(float a, float b) {
  return __builtin_bit_cast(unsigned, __builtin_amdgcn_cvt_pkrtz(a, b));
}

// v_permlane32_swap_b32: a.hi(lanes32-63) <-> b.lo(lanes0-31)
// Only safe when a and b hold DISTINCT values (r13: same-value operands got
// coalesced into a self-swap). Single-value cross-lane reductions: __shfl_xor.
__device__ __forceinline__ void plswap(unsigned &a, unsigned &b) {
  asm volatile("v_permlane32_swap_b32 %0, %1" : "+v"(a), "+v"(b));
}

__device__ __forceinline__ f32x16 mfma16(half8 a, half8 b, f32x16 c) {
  return __builtin_amdgcn_mfma_f32_32x32x16_f16(a, b, c, 0, 0, 0);
}

// Build the B-operand fragment (k = 8h+j within a 16-k block) from 8 C-layout
// register values p0..p7 (rows crow(r,h) = (r&3)+8*(r>>2)+4h).  m214 recipe.
__device__ __forceinline__ half8 pack_frag(float p0, float p1, float p2, float p3,
                                           float p4, float p5, float p6, float p7) {
  unsigned a0 = pk16(p0, p1), a1 = pk16(p2, p3);
  unsigned b0 = pk16(p4, p5), b1 = pk16(p6, p7);
  plswap(a0, b0);
  plswap(a1, b1);
  uv4 u; u.x = a0; u.y = a1; u.z = b0; u.w = b1;
  return __builtin_bit_cast(half8, u);
}

// ---------------------------------------------------------------------------
// prep: Q = (x@W1^T)*log2e, K = x@W2^T (fp32 accum -> f16), VT[b][d][n]=f16(x)
// 32-row tiles, grid = 4*256 = 1024 (4 blocks/CU).
// ---------------------------------------------------------------------------
__global__ __launch_bounds__(256) void prep_kernel(
    const float* __restrict__ x, const float* __restrict__ W1,
    const float* __restrict__ W2, _Float16* __restrict__ Qg,
    _Float16* __restrict__ Kg, _Float16* __restrict__ VTg) {
  __shared__ float xs[32][68];
  __shared__ float w1s[64][68];
  __shared__ float w2s[64][68];
  const int tid = threadIdx.x;
  const int b = blockIdx.x >> 8;
  const int n0 = (blockIdx.x & 255) << 5;
  const float* xp = x + (size_t)(b * 8192 + n0) * 64;
  for (int i = tid; i < 2048; i += 256) xs[i >> 6][i & 63] = xp[i];
  for (int i = tid; i < 4096; i += 256) {
    w1s[i >> 6][i & 63] = W1[i];
    w2s[i >> 6][i & 63] = W2[i];
  }
  __syncthreads();

  const int e = tid & 63, r0 = tid >> 6;
  float qa[8], ka[8];
#pragma unroll
  for (int r = 0; r < 8; ++r) { qa[r] = 0.f; ka[r] = 0.f; }
#pragma unroll 1
  for (int dc = 0; dc < 4; ++dc) {
    float4 w1c[4], w2c[4];
#pragma unroll
    for (int i = 0; i < 4; ++i) {
      w1c[i] = *(const float4*)&w1s[e][dc * 16 + i * 4];
      w2c[i] = *(const float4*)&w2s[e][dc * 16 + i * 4];
    }
#pragma unroll
    for (int rr = 0; rr < 8; ++rr) {
      const int r = (rr << 2) | r0;
#pragma unroll
      for (int i = 0; i < 4; ++i) {
        float4 xv = *(const float4*)&xs[r][dc * 16 + i * 4];
        qa[rr] = fmaf(xv.x, w1c[i].x, qa[rr]);
        qa[rr] = fmaf(xv.y, w1c[i].y, qa[rr]);
        qa[rr] = fmaf(xv.z, w1c[i].z, qa[rr]);
        qa[rr] = fmaf(xv.w, w1c[i].w, qa[rr]);
        ka[rr] = fmaf(xv.x, w2c[i].x, ka[rr]);
        ka[rr] = fmaf(xv.y, w2c[i].y, ka[rr]);
        ka[rr] = fmaf(xv.z, w2c[i].z, ka[rr]);
        ka[rr] = fmaf(xv.w, w2c[i].w, ka[rr]);
      }
    }
  }
#pragma unroll
  for (int rr = 0; rr < 8; ++rr) {
    const int r = (rr << 2) | r0;
    size_t o = (size_t)(b * 8192 + n0 + r) * 64 + e;
    Qg[o] = (_Float16)(qa[rr] * LOG2E);
    Kg[o] = (_Float16)ka[rr];
  }
  // VT: transpose x tile, f16. thread -> d = tid/4, 8-row chunk = tid&3
  const int d = tid >> 2, c = tid & 3;
  half8 v;
#pragma unroll
  for (int i = 0; i < 8; ++i) v[i] = (_Float16)xs[(c << 3) + i][d];
  *(half8*)(VTg + (size_t)(b * 64 + d) * 8192 + n0 + (c << 3)) = v;
}

// ---------------------------------------------------------------------------
// attn: flash attention, swapped QK^T (ST = mfma(K,Q)), fused GCN epilogue.
// ROUND-18: NO LDS, NO BARRIERS. K/V working set is L2/L3-resident (FETCH =
// 12.4MB all session) -- LDS staging + block-wide lock-step barriers were the
// diagnosed stall (r10-r17: every occupancy/LDS/VALU lever lands at 100-110us,
// pipe sums say ~40us overlapped). Each wave now reads its K/V fragments
// DIRECTLY from global (per-lane 16B gathers, 128B row stride; every touched
// line fully consumed per tile across kb/h) and free-runs -- no __syncthreads,
// no vmcnt choreography, wave-scheduler handles all overlap.
// Structure: r16's verified half-tile math (one 16-reg st live), 4-wave
// blocks, QBLK=128, grid = S*256 = 4 blocks/CU, (256,4) reg cap (r8: this
// body fits at 52 VGPR clean). Log2-domain softmax, defer-max THR=8,
// deferred lsum merge, XCD-chunked swizzle. S in {1,2,4}.
// ---------------------------------------------------------------------------
__global__ __launch_bounds__(256, 4) void attn_kernel(
    const _Float16* __restrict__ Qg, const _Float16* __restrict__ Kg,
    const _Float16* __restrict__ VTg, const float* __restrict__ Gw,
    float* __restrict__ out, _Float16* __restrict__ Zp,
    float* __restrict__ Ma, float* __restrict__ La, int ntiles, int S) {
  const int tid = threadIdx.x;
  const int w = tid >> 6;   // 0..3
  const int l = tid & 63;
  const int h = l >> 5;
  const int r31 = l & 31;
  // XCD-chunked bid swizzle (T1). nwg = S*256, always divisible by 8.
  const int nwg = gridDim.x;
  const int hw = blockIdx.x;
  const int bid = (hw & 7) * (nwg >> 3) + (hw >> 3);
  const int qblk = bid & 63;            // 64 q-blocks of 128 rows
  const int b = (bid >> 6) & 3;
  const int s = bid >> 8;
  const int kv0 = s * ntiles * 64;      // first kv row of this split
  const int qrow = (qblk << 7) + (w << 5) + r31;

  // Q fragments: B-operand layout (col=q=l&31, k = kb*16 + 8h + j)
  half8 qf[4];
  {
    const _Float16* qp = Qg + ((size_t)(b * 8192 + qrow) << 6) + (h << 3);
#pragma unroll
    for (int kb = 0; kb < 4; ++kb) qf[kb] = *(const half8*)(qp + (kb << 4));
  }

  f32x16 o0 = (f32x16)0.f, o1 = (f32x16)0.f;
  float m = -INFINITY, lsum = 0.f;   // lsum: per-lane partial (merged at end)

  // per-lane global base pointers (linear layout, no swizzle needed):
  // K[b][kv0 + trow][d]: row stride 128B; lane reads rows r31 / 32+r31,
  // column (kb*16 + h*8) halfs.
  const char* pKbase = (const char*)Kg +
      (((size_t)(b * 8192 + kv0) + r31) << 7) + (h << 4);
  // VT[b][d][n]: d-row stride 16384B; lane reads d-rows r31 / 32+r31,
  // kv column (kv0 + t*64 + kb*16 + h*8) halfs.
  const char* pVbase = (const char*)VTg +
      (((size_t)(b * 64 + r31)) << 14) + ((size_t)kv0 << 1) + (h << 4);

#pragma unroll 1
  for (int t = 0; t < ntiles; ++t) {
    const char* pK = pKbase + ((size_t)t << 13);  // t*64 rows * 128B
    const char* pV = pVbase + ((size_t)t << 7);   // t*64 halfs * 2B

#pragma unroll
    for (int hf = 0; hf < 2; ++hf) {
      // ---- ST-half = K . Q^T : lane q = l&31, kv = 32*hf + crow(r,h)
      f32x16 st = (f32x16)0.f;
      __builtin_amdgcn_s_setprio(1);
#pragma unroll
      for (int kb = 0; kb < 4; ++kb) {
        half8 kf = *(const half8*)(pK + (hf << 12) + (kb << 5));
        st = mfma16(kf, qf[kb], st);
      }
      __builtin_amdgcn_s_setprio(0);

      // ---- online softmax (log2 domain); defer-max (T13, THR=8)
      float mx[8];
#pragma unroll
      for (int r = 0; r < 8; ++r) mx[r] = fmaxf(st[r], st[r + 8]);
      float pm = fmaxf(fmaxf(fmaxf(mx[0], mx[1]), fmaxf(mx[2], mx[3])),
                       fmaxf(fmaxf(mx[4], mx[5]), fmaxf(mx[6], mx[7])));
      pm = fmaxf(pm, __shfl_xor(pm, 32));
      if (__any(pm > m + 8.f)) {
        float mn = fmaxf(m, pm);
        float sc = __builtin_amdgcn_exp2f(m - mn);
#pragma unroll
        for (int r = 0; r < 16; ++r) { o0[r] *= sc; o1[r] *= sc; }
        lsum *= sc;
        m = mn;
      }
#pragma unroll
      for (int r = 0; r < 16; ++r) st[r] = __builtin_amdgcn_exp2f(st[r] - m);

      // ---- lsum: per-lane partial only (cross-lane merge deferred to end)
      float sm[8];
#pragma unroll
      for (int r = 0; r < 8; ++r) sm[r] = st[r] + st[r + 8];
      sm[0] += sm[4]; sm[1] += sm[5]; sm[2] += sm[6]; sm[3] += sm[7];
      sm[0] += sm[2]; sm[1] += sm[3];
      lsum += sm[0] + sm[1];

      // ---- P-half -> f16 B-fragments (cvt_pk + permlane32_swap)
      half8 pf0 = pack_frag(st[0], st[1], st[2], st[3], st[4], st[5], st[6], st[7]);
      half8 pf1 = pack_frag(st[8], st[9], st[10], st[11], st[12], st[13], st[14], st[15]);

      // ---- O^T += V^T-half . P^T-half  (kv blocks 2*hf, 2*hf+1)
      __builtin_amdgcn_s_setprio(1);
#pragma unroll
      for (int j = 0; j < 2; ++j) {
        const int kb = (hf << 1) | j;
        half8 v0 = *(const half8*)(pV + (kb << 5));
        half8 v1 = *(const half8*)(pV + ((size_t)1 << 19) + (kb << 5));
        o0 = mfma16(v0, j == 0 ? pf0 : pf1, o0);
        o1 = mfma16(v1, j == 0 ? pf0 : pf1, o1);
      }
      __builtin_amdgcn_s_setprio(0);
    }
  }

  // ---- epilogue: merge lsum across lane^32, normalize, fused GCN, store
  lsum += __shfl_xor(lsum, 32);
  const float inv = 1.f / lsum;
#pragma unroll
  for (int r = 0; r < 16; ++r) { o0[r] *= inv; o1[r] *= inv; }

  half8 of[4];
  of[0] = pack_frag(o0[0], o0[1], o0[2], o0[3], o0[4], o0[5], o0[6], o0[7]);
  of[1] = pack_frag(o0[8], o0[9], o0[10], o0[11], o0[12], o0[13], o0[14], o0[15]);
  of[2] = pack_frag(o1[0], o1[1], o1[2], o1[3], o1[4], o1[5], o1[6], o1[7]);
  of[3] = pack_frag(o1[8], o1[9], o1[10], o1[11], o1[12], o1[13], o1[14], o1[15]);
  f32x16 z0 = (f32x16)0.f, z1 = (f32x16)0.f;
#pragma unroll
  for (int eb = 0; eb < 2; ++eb) {
#pragma unroll
    for (int kb = 0; kb < 4; ++kb) {
      half8 tt;
#pragma unroll
      for (int j = 0; j < 8; ++j) {
        int dd = (kb << 4) + (h << 3) + j;
        tt[j] = (_Float16)Gw[(dd << 6) + (eb << 5) + r31];
      }
      if (eb == 0) z0 = mfma16(tt, of[kb], z0);
      else         z1 = mfma16(tt, of[kb], z1);
    }
  }
  if (S == 1) {
    float* Orow = out + (size_t)(b * 8192 + qrow) * 64;
#pragma unroll
    for (int r = 0; r < 16; ++r) {
      const int e0 = (r & 3) + ((r >> 2) << 3) + (h << 2);
      Orow[e0] = fmaxf(z0[r], 0.f);
      Orow[e0 + 32] = fmaxf(z1[r], 0.f);
    }
  } else {
    _Float16* Zrow = Zp + ((size_t)((s << 2) + b) * 8192 + qrow) * 64;
#pragma unroll
    for (int r = 0; r < 16; ++r) {
      const int e0 = (r & 3) + ((r >> 2) << 3) + (h << 2);
      Zrow[e0] = (_Float16)z0[r];
      Zrow[e0 + 32] = (_Float16)z1[r];
    }
    if (h == 0) {
      size_t si = (size_t)((s << 2) + b) * 8192 + qrow;
      Ma[si] = m;   // log2-domain running max
      La[si] = lsum;
    }
  }
}

// ---------------------------------------------------------------------------
// merge: combine S splits + relu. Ma is log2-domain -> a = exp2(Ma-M)*La.
// ---------------------------------------------------------------------------
template <int S>
__global__ __launch_bounds__(256) void merge_kernel(
    const _Float16* __restrict__ Zp, const float* __restrict__ Ma,
    const float* __restrict__ La, float* __restrict__ out) {
  const int idx = blockIdx.x * 256 + threadIdx.x;  // quad index
  const int R = idx >> 4;
  const int c4 = (idx & 15) << 2;
  float M = -INFINITY;
#pragma unroll
  for (int s = 0; s < S; ++s) M = fmaxf(M, Ma[R + s * 32768]);
  float a[S];
  float asum = 0.f;
#pragma unroll
  for (int s = 0; s < S; ++s) {
    a[s] = __builtin_amdgcn_exp2f(Ma[R + s * 32768] - M) * La[R + s * 32768];
    asum += a[s];
  }
  const float inv = 1.f / asum;
  float4 acc = make_float4(0.f, 0.f, 0.f, 0.f);
#pragma unroll
  for (int s = 0; s < S; ++s) {
    const half4v z = *(const half4v*)(Zp + ((size_t)(R + s * 32768) * 64 + c4));
    const float as = a[s];
    acc.x = fmaf(as, (float)z[0], acc.x);
    acc.y = fmaf(as, (float)z[1], acc.y);
    acc.z = fmaf(as, (float)z[2], acc.z);
    acc.w = fmaf(as, (float)z[3], acc.w);
  }
  float4 y;
  y.x = fmaxf(acc.x * inv, 0.f);
  y.y = fmaxf(acc.y * inv, 0.f);
  y.z = fmaxf(acc.z * inv, 0.f);
  y.w = fmaxf(acc.w * inv, 0.f);
  *(float4*)(out + (size_t)R * 64 + c4) = y;
}

extern "C" void kernel_launch(void* const* d_in, const int* in_sizes, int n_in,
                              void* d_out, int out_size, void* d_ws, size_t ws_size,
                              hipStream_t stream) {
  const float* x = (const float*)d_in[0];
  const float* W1 = (const float*)d_in[1];
  const float* W2 = (const float*)d_in[2];
  const float* G = (const float*)d_in[3];
  char* ws = (char*)d_ws;
  const size_t MB = (size_t)1 << 20;
  _Float16* Qg = (_Float16*)(ws);
  _Float16* Kg = (_Float16*)(ws + 4 * MB);
  _Float16* VTg = (_Float16*)(ws + 8 * MB);
  float* out = (float*)d_out;

  // KV-split factor gated on workspace size (Zp f16, S*4MB; Ma/La S*0.25MB):
  //   S=4 needs 12 + 16 + 1 = 29MB ; S=2 needs 20.5MB
  int S;
  if (ws_size >= 30 * MB) S = 4;
  else if (ws_size >= 21 * MB) S = 2;
  else S = 1;

  _Float16* Zp = (_Float16*)(ws + 12 * MB);
  float* Ma = (float*)(ws + 12 * MB + (size_t)S * 4 * MB);
  float* La = Ma + (size_t)S * 32768;

  prep_kernel<<<dim3(1024), dim3(256), 0, stream>>>(x, W1, W2, Qg, Kg, VTg);
  // grid = S * 4 batches * 64 qblks(128 rows each, 4 waves) ; ntiles = 128/S
  attn_kernel<<<dim3(S * 256), dim3(256), 0, stream>>>(Qg, Kg, VTg, G, out, Zp,
                                                       Ma, La, 128 / S, S);
  if (S == 4)
    merge_kernel<4><<<dim3(2048), dim3(256), 0, stream>>>(Zp, Ma, La, out);
  else if (S == 2)
    merge_kernel<2><<<dim3(2048), dim3(256), 0, stream>>>(Zp, Ma, La, out);
}

// Round 19
// 115.338 us; speedup vs baseline: 2.2573x; 2.2573x over previous
//
#include <hip/hip_runtime.h>

#define LOG2E 1.44269504088896340736f

typedef _Float16 half8 __attribute__((ext_vector_type(8)));
typedef _Float16 half4v __attribute__((ext_vector_type(4)));
typedef float f32x16 __attribute__((ext_vector_type(16)));
typedef unsigned int uv4 __attribute__((ext_vector_type(4)));

__device__ __forceinline__ unsigned pk16(float a, float b) {
  return __builtin_bit_cast(unsigned, __builtin_amdgcn_cvt_pkrtz(a, b));
}

// v_permlane32_swap_b32: a.hi(lanes32-63) <-> b.lo(lanes0-31)
// Only safe when a and b hold DISTINCT values (r13: same-value operands got
// coalesced into a self-swap). Single-value cross-lane reductions: __shfl_xor.
__device__ __forceinline__ void plswap(unsigned &a, unsigned &b) {
  asm volatile("v_permlane32_swap_b32 %0, %1" : "+v"(a), "+v"(b));
}

__device__ __forceinline__ f32x16 mfma16(half8 a, half8 b, f32x16 c) {
  return __builtin_amdgcn_mfma_f32_32x32x16_f16(a, b, c, 0, 0, 0);
}

// Build the B-operand fragment (k = 8h+j within a 16-k block) from 8 C-layout
// register values p0..p7 (rows crow(r,h) = (r&3)+8*(r>>2)+4h).  m214 recipe.
__device__ __forceinline__ half8 pack_frag(float p0, float p1, float p2, float p3,
                                           float p4, float p5, float p6, float p7) {
  unsigned a0 = pk16(p0, p1), a1 = pk16(p2, p3);
  unsigned b0 = pk16(p4, p5), b1 = pk16(p6, p7);
  plswap(a0, b0);
  plswap(a1, b1);
  uv4 u; u.x = a0; u.y = a1; u.z = b0; u.w = b1;
  return __builtin_bit_cast(half8, u);
}

// ---------------------------------------------------------------------------
// prep: Q = (x@W1^T)*log2e, K = x@W2^T (fp32 accum -> f16), VT[b][d][n]=f16(x)
// Q pre-scaled by log2e so attn's softmax runs natively in the exp2 domain.
// block: 256 threads, one 64-row n-tile of one batch. grid = 4*128 = 512.
// ---------------------------------------------------------------------------
__global__ __launch_bounds__(256) void prep_kernel(
    const float* __restrict__ x, const float* __restrict__ W1,
    const float* __restrict__ W2, _Float16* __restrict__ Qg,
    _Float16* __restrict__ Kg, _Float16* __restrict__ VTg) {
  __shared__ float xs[64][68];
  __shared__ float w1s[64][68];
  __shared__ float w2s[64][68];
  const int tid = threadIdx.x;
  const int b = blockIdx.x >> 7;
  const int n0 = (blockIdx.x & 127) << 6;
  const float* xp = x + (size_t)(b * 8192 + n0) * 64;
  for (int i = tid; i < 4096; i += 256) {
    int r = i >> 6, c = i & 63;
    xs[r][c] = xp[i];
    w1s[r][c] = W1[i];
    w2s[r][c] = W2[i];
  }
  __syncthreads();

  const int e = tid & 63, r0 = tid >> 6;
  float qa[16], ka[16];
#pragma unroll
  for (int r = 0; r < 16; ++r) { qa[r] = 0.f; ka[r] = 0.f; }
#pragma unroll 1
  for (int dc = 0; dc < 4; ++dc) {
    float4 w1c[4], w2c[4];
#pragma unroll
    for (int i = 0; i < 4; ++i) {
      w1c[i] = *(const float4*)&w1s[e][dc * 16 + i * 4];
      w2c[i] = *(const float4*)&w2s[e][dc * 16 + i * 4];
    }
#pragma unroll
    for (int rr = 0; rr < 16; ++rr) {
      const int r = (rr << 2) | r0;
#pragma unroll
      for (int i = 0; i < 4; ++i) {
        float4 xv = *(const float4*)&xs[r][dc * 16 + i * 4];
        qa[rr] = fmaf(xv.x, w1c[i].x, qa[rr]);
        qa[rr] = fmaf(xv.y, w1c[i].y, qa[rr]);
        qa[rr] = fmaf(xv.z, w1c[i].z, qa[rr]);
        qa[rr] = fmaf(xv.w, w1c[i].w, qa[rr]);
        ka[rr] = fmaf(xv.x, w2c[i].x, ka[rr]);
        ka[rr] = fmaf(xv.y, w2c[i].y, ka[rr]);
        ka[rr] = fmaf(xv.z, w2c[i].z, ka[rr]);
        ka[rr] = fmaf(xv.w, w2c[i].w, ka[rr]);
      }
    }
  }
#pragma unroll
  for (int rr = 0; rr < 16; ++rr) {
    const int r = (rr << 2) | r0;
    size_t o = (size_t)(b * 8192 + n0 + r) * 64 + e;
    Qg[o] = (_Float16)(qa[rr] * LOG2E);
    Kg[o] = (_Float16)ka[rr];
  }
  const int d = tid >> 2, nc = (tid & 3) << 4;
  half8 v0, v1;
#pragma unroll
  for (int i = 0; i < 8; ++i) {
    v0[i] = (_Float16)xs[nc + i][d];
    v1[i] = (_Float16)xs[nc + 8 + i][d];
  }
  _Float16* vp = VTg + (size_t)(b * 64 + d) * 8192 + n0 + nc;
  *(half8*)vp = v0;
  *(half8*)(vp + 8) = v1;
}

// ---------------------------------------------------------------------------
// attn: flash attention, swapped QK^T (ST = mfma(K,Q)), fused GCN epilogue.
// FINAL = r14, the measured session optimum (attn 99.7us, total 115.5us).
// Session evidence (r10-r18): occupancy up (r18: 46%, 253us) and down (r10:
// 11%, 154us), LDS traffic halved (r12), VALU cuts (r6/r8), barrier halving
// (r14: the one win), chain re-order (r15), no-LDS direct-gather (r18: TA-
// request-bound disaster) -- all confirm this structure is the plain-HIP
// floor at ~0.69 PF effective for D=64. Remaining gap to pipe-sum floor
// (~40us) requires asm-level scheduling (AITER/HK-class), out of HIP reach.
// Structure: log2-domain softmax (Q pre-scaled), defer-max THR=8, deferred
// lsum merge, TRIPLE-buffered LDS with ONE barrier per tile, counted
// vmcnt(2), 8-wave blocks, QBLK=256, KVBLK=64, r9-verified staging swizzle.
// ---------------------------------------------------------------------------
#define GL(src, dst)                                                           \
  __builtin_amdgcn_global_load_lds(                                            \
      (const __attribute__((address_space(1))) unsigned*)(src),                \
      (__attribute__((address_space(3))) unsigned*)(dst), 16, 0, 0)

#define STAGE(buf, t)                                                          \
  {                                                                            \
    GL(srcK0 + ((size_t)(t) << 13), &sK[buf][w << 9]);                         \
    GL(srcV0 + ((size_t)(t) << 7), &sV[buf][w << 9]);                          \
  }

#define VMCNT2() asm volatile("s_waitcnt vmcnt(2)" ::: "memory")
#define VMCNT0() asm volatile("s_waitcnt vmcnt(0)" ::: "memory")

__global__ __launch_bounds__(512, 4) void attn_kernel(
    const _Float16* __restrict__ Qg, const _Float16* __restrict__ Kg,
    const _Float16* __restrict__ VTg, const float* __restrict__ Gw,
    float* __restrict__ out, _Float16* __restrict__ Zp,
    float* __restrict__ Ma, float* __restrict__ La, int ntiles, int S) {
  __shared__ _Float16 sK[3][4096];
  __shared__ _Float16 sV[3][4096];
  const int tid = threadIdx.x;
  const int w = tid >> 6;   // 0..7
  const int l = tid & 63;
  const int h = l >> 5;
  const int r31 = l & 31;
  // XCD-chunked bid swizzle (T1). nwg = S*128, always divisible by 8.
  const int nwg = gridDim.x;
  const int hw = blockIdx.x;
  const int bid = (hw & 7) * (nwg >> 3) + (hw >> 3);
  const int qblk = bid & 31;            // 32 q-blocks of 256 rows
  const int b = (bid >> 5) & 3;
  const int s = bid >> 7;
  const int kv0 = s * ntiles * 64;      // first kv row of this split
  const int qrow = (qblk << 8) + (w << 5) + r31;

  // Q fragments: B-operand layout (col=q=l&31, k = kb*16 + 8h + j)
  half8 qf[4];
  {
    const _Float16* qp = Qg + ((size_t)(b * 8192 + qrow) << 6) + (h << 3);
#pragma unroll
    for (int kb = 0; kb < 4; ++kb) qf[kb] = *(const half8*)(qp + (kb << 4));
  }

  f32x16 o0 = (f32x16)0.f, o1 = (f32x16)0.f;
  float m = -INFINITY, lsum = 0.f;   // lsum: per-lane partial (merged at end)

  // staging: wave w covers rows w*8 + (l>>3); swizzled source chunk
  const int srow = (w << 3) | (l >> 3);
  const int sblk = (l & 7) ^ (l >> 3);
  const char* srcK0 =
      (const char*)(Kg + ((size_t)(b * 8192 + kv0 + srow) << 6)) + (sblk << 4);
  const char* srcV0 =
      (const char*)(VTg + ((size_t)(b * 64 + srow) << 13) + kv0) + (sblk << 4);

  // prologue: prefetch tiles 0 and 1 (depth 2), wait only for tile 0.
  STAGE(0, 0);
  STAGE(1, 1);
  VMCNT2();
  __builtin_amdgcn_s_barrier();

  int cur = 0, stg = 2;  // compute buffer / stage target ((t+2)%3)
#pragma unroll 1
  for (int t = 0; t < ntiles; ++t) {
    const char* pK = (const char*)sK[cur];
    const char* pV = (const char*)sV[cur];

    // ---- ST = K . Q^T : lane has q = l&31, kv = crow(r,h) (+32 for st1)
    f32x16 st0 = (f32x16)0.f, st1 = (f32x16)0.f;
    __builtin_amdgcn_s_setprio(1);
#pragma unroll
    for (int kb = 0; kb < 4; ++kb) {
      const int sl = ((((kb << 1) | h)) ^ (r31 & 7)) << 4;
      half8 k0 = *(const half8*)(pK + (r31 << 7) + sl);
      half8 k1 = *(const half8*)(pK + ((32 + r31) << 7) + sl);
      st0 = mfma16(k0, qf[kb], st0);
      st1 = mfma16(k1, qf[kb], st1);
    }
    __builtin_amdgcn_s_setprio(0);

    // ---- online softmax (log2 domain); defer-max (T13, THR=8)
    float mx[8];
#pragma unroll
    for (int r = 0; r < 8; ++r)
      mx[r] = fmaxf(fmaxf(st0[r], st0[r + 8]), fmaxf(st1[r], st1[r + 8]));
    float pm = fmaxf(fmaxf(fmaxf(mx[0], mx[1]), fmaxf(mx[2], mx[3])),
                     fmaxf(fmaxf(mx[4], mx[5]), fmaxf(mx[6], mx[7])));
    pm = fmaxf(pm, __shfl_xor(pm, 32));  // pair merge (proven path)
    if (__any(pm > m + 8.f)) {
      float mn = fmaxf(m, pm);
      float sc = __builtin_amdgcn_exp2f(m - mn);
#pragma unroll
      for (int r = 0; r < 16; ++r) { o0[r] *= sc; o1[r] *= sc; }
      lsum *= sc;
      m = mn;
    }
#pragma unroll
    for (int r = 0; r < 16; ++r) {
      st0[r] = __builtin_amdgcn_exp2f(st0[r] - m);
      st1[r] = __builtin_amdgcn_exp2f(st1[r] - m);
    }

    // ---- lsum: per-lane partial only (cross-lane merge deferred to end;
    // rescale-consistent because m is pair-uniform)
    float sm[8];
#pragma unroll
    for (int r = 0; r < 8; ++r) sm[r] = (st0[r] + st0[r + 8]) + (st1[r] + st1[r + 8]);
    sm[0] += sm[4]; sm[1] += sm[5]; sm[2] += sm[6]; sm[3] += sm[7];
    sm[0] += sm[2]; sm[1] += sm[3];
    lsum += sm[0] + sm[1];

    // ---- P -> f16 B-fragments (cvt_pk + permlane32_swap)
    half8 pf0 = pack_frag(st0[0], st0[1], st0[2], st0[3], st0[4], st0[5], st0[6], st0[7]);
    half8 pf1 = pack_frag(st0[8], st0[9], st0[10], st0[11], st0[12], st0[13], st0[14], st0[15]);
    half8 pf2 = pack_frag(st1[0], st1[1], st1[2], st1[3], st1[4], st1[5], st1[6], st1[7]);
    half8 pf3 = pack_frag(st1[8], st1[9], st1[10], st1[11], st1[12], st1[13], st1[14], st1[15]);

    // ---- O^T += V^T . P^T
    __builtin_amdgcn_s_setprio(1);
#pragma unroll
    for (int kb = 0; kb < 4; ++kb) {
      const int sl = ((((kb << 1) | h)) ^ (r31 & 7)) << 4;
      half8 v0 = *(const half8*)(pV + (r31 << 7) + sl);
      half8 v1 = *(const half8*)(pV + ((32 + r31) << 7) + sl);
      half8 pf = kb == 0 ? pf0 : kb == 1 ? pf1 : kb == 2 ? pf2 : pf3;
      o0 = mfma16(v0, pf, o0);
      o1 = mfma16(v1, pf, o1);
    }
    __builtin_amdgcn_s_setprio(0);

    // ---- single pipeline boundary (3-buffer): stage t+2 into the buffer
    // last read at tile t-1; vmcnt(2) drains t+1's loads; one barrier makes
    // them visible block-wide. No WAR hazard: nobody reads buf[stg] now.
    if (t + 2 < ntiles) {
      STAGE(stg, t + 2);
      VMCNT2();
    } else {
      VMCNT0();
    }
    __builtin_amdgcn_s_barrier();
    cur = (cur == 2) ? 0 : cur + 1;
    stg = (stg == 2) ? 0 : stg + 1;
  }

  // ---- epilogue: merge lsum across lane^32, normalize, fused GCN, store
  lsum += __shfl_xor(lsum, 32);
  const float inv = 1.f / lsum;
#pragma unroll
  for (int r = 0; r < 16; ++r) { o0[r] *= inv; o1[r] *= inv; }

  half8 of[4];
  of[0] = pack_frag(o0[0], o0[1], o0[2], o0[3], o0[4], o0[5], o0[6], o0[7]);
  of[1] = pack_frag(o0[8], o0[9], o0[10], o0[11], o0[12], o0[13], o0[14], o0[15]);
  of[2] = pack_frag(o1[0], o1[1], o1[2], o1[3], o1[4], o1[5], o1[6], o1[7]);
  of[3] = pack_frag(o1[8], o1[9], o1[10], o1[11], o1[12], o1[13], o1[14], o1[15]);
  f32x16 z0 = (f32x16)0.f, z1 = (f32x16)0.f;
#pragma unroll
  for (int eb = 0; eb < 2; ++eb) {
#pragma unroll
    for (int kb = 0; kb < 4; ++kb) {
      half8 tt;
#pragma unroll
      for (int j = 0; j < 8; ++j) {
        int dd = (kb << 4) + (h << 3) + j;
        tt[j] = (_Float16)Gw[(dd << 6) + (eb << 5) + r31];
      }
      if (eb == 0) z0 = mfma16(tt, of[kb], z0);
      else         z1 = mfma16(tt, of[kb], z1);
    }
  }
  if (S == 1) {
    float* Orow = out + (size_t)(b * 8192 + qrow) * 64;
#pragma unroll
    for (int r = 0; r < 16; ++r) {
      const int e0 = (r & 3) + ((r >> 2) << 3) + (h << 2);
      Orow[e0] = fmaxf(z0[r], 0.f);
      Orow[e0 + 32] = fmaxf(z1[r], 0.f);
    }
  } else {
    _Float16* Zrow = Zp + ((size_t)((s << 2) + b) * 8192 + qrow) * 64;
#pragma unroll
    for (int r = 0; r < 16; ++r) {
      const int e0 = (r & 3) + ((r >> 2) << 3) + (h << 2);
      Zrow[e0] = (_Float16)z0[r];
      Zrow[e0 + 32] = (_Float16)z1[r];
    }
    if (h == 0) {
      size_t si = (size_t)((s << 2) + b) * 8192 + qrow;
      Ma[si] = m;   // log2-domain running max
      La[si] = lsum;
    }
  }
}

// ---------------------------------------------------------------------------
// merge: combine S splits + relu. Ma is log2-domain -> a = exp2(Ma-M)*La.
// ---------------------------------------------------------------------------
template <int S>
__global__ __launch_bounds__(256) void merge_kernel(
    const _Float16* __restrict__ Zp, const float* __restrict__ Ma,
    const float* __restrict__ La, float* __restrict__ out) {
  const int idx = blockIdx.x * 256 + threadIdx.x;  // quad index
  const int R = idx >> 4;
  const int c4 = (idx & 15) << 2;
  float M = -INFINITY;
#pragma unroll
  for (int s = 0; s < S; ++s) M = fmaxf(M, Ma[R + s * 32768]);
  float a[S];
  float asum = 0.f;
#pragma unroll
  for (int s = 0; s < S; ++s) {
    a[s] = __builtin_amdgcn_exp2f(Ma[R + s * 32768] - M) * La[R + s * 32768];
    asum += a[s];
  }
  const float inv = 1.f / asum;
  float4 acc = make_float4(0.f, 0.f, 0.f, 0.f);
#pragma unroll
  for (int s = 0; s < S; ++s) {
    const half4v z = *(const half4v*)(Zp + ((size_t)(R + s * 32768) * 64 + c4));
    const float as = a[s];
    acc.x = fmaf(as, (float)z[0], acc.x);
    acc.y = fmaf(as, (float)z[1], acc.y);
    acc.z = fmaf(as, (float)z[2], acc.z);
    acc.w = fmaf(as, (float)z[3], acc.w);
  }
  float4 y;
  y.x = fmaxf(acc.x * inv, 0.f);
  y.y = fmaxf(acc.y * inv, 0.f);
  y.z = fmaxf(acc.z * inv, 0.f);
  y.w = fmaxf(acc.w * inv, 0.f);
  *(float4*)(out + (size_t)R * 64 + c4) = y;
}

extern "C" void kernel_launch(void* const* d_in, const int* in_sizes, int n_in,
                              void* d_out, int out_size, void* d_ws, size_t ws_size,
                              hipStream_t stream) {
  const float* x = (const float*)d_in[0];
  const float* W1 = (const float*)d_in[1];
  const float* W2 = (const float*)d_in[2];
  const float* G = (const float*)d_in[3];
  char* ws = (char*)d_ws;
  const size_t MB = (size_t)1 << 20;
  _Float16* Qg = (_Float16*)(ws);
  _Float16* Kg = (_Float16*)(ws + 4 * MB);
  _Float16* VTg = (_Float16*)(ws + 8 * MB);
  float* out = (float*)d_out;

  // KV-split factor gated on workspace size (Zp f16, S*4MB; Ma/La S*0.25MB):
  //   S=4 needs 12 + 16 + 1 = 29MB ; S=2 needs 20.5MB
  int S;
  if (ws_size >= 30 * MB) S = 4;
  else if (ws_size >= 21 * MB) S = 2;
  else S = 1;

  _Float16* Zp = (_Float16*)(ws + 12 * MB);
  float* Ma = (float*)(ws + 12 * MB + (size_t)S * 4 * MB);
  float* La = Ma + (size_t)S * 32768;

  prep_kernel<<<dim3(512), dim3(256), 0, stream>>>(x, W1, W2, Qg, Kg, VTg);
  // grid = S * 4 batches * 32 qblks(256 rows each, 8 waves) ; ntiles = 128/S
  attn_kernel<<<dim3(S * 128), dim3(512), 0, stream>>>(Qg, Kg, VTg, G, out, Zp,
                                                       Ma, La, 128 / S, S);
  if (S == 4)
    merge_kernel<4><<<dim3(2048), dim3(256), 0, stream>>>(Zp, Ma, La, out);
  else if (S == 2)
    merge_kernel<2><<<dim3(2048), dim3(256), 0, stream>>>(Zp, Ma, La, out);
}